// Round 6
// baseline (19.145 us; speedup 1.0000x reference)
//
#include <hip/hip_runtime.h>
#include <math.h>

// Siddon exact forward projector — incremental (Amanatides-Woo) traversal.
// Block = 512 threads = 8 waves = 64 consecutive rays; SPLIT=16 t-sub-ranges
// per ray; each lane runs TWO independent DDA streams (sub and sub+8).
// Two gathers in flight per wave doubles memory-level parallelism: the
// issue->use distance per load is ~2 iterations x 8 waves of VALU, hiding
// far-L2/L3 latency that one-deep pipelining could not.

constexpr int      NV    = 128;
constexpr int      NVSQ  = NV * NV;
constexpr unsigned NV3   = (unsigned)NV * NV * NV;
constexpr float    EPS_F = 1e-12f;
constexpr float    BIG_F = 1e9f;
constexpr int      SPLIT = 16;   // sub-ranges per ray (2 per wave)
constexpr int      RPB   = 64;   // rays per block (= lanes per wave)
constexpr int      WPB   = 8;    // waves per block

__global__ __launch_bounds__(512)
void siddon_fwd_kernel(const float* __restrict__ vol,
                       const float* __restrict__ Mptr,
                       const float* __restrict__ bptr,
                       const float* __restrict__ src,
                       const float* __restrict__ dst,
                       float* __restrict__ out,
                       int n_ray)
{
    int lane = threadIdx.x & 63;
    int sub  = threadIdx.x >> 6;            // 0..7; streams use sub and sub+8

    // ---- XCD-aware block swizzle (bijective when gridDim.x % 8 == 0) ----
    int bid = blockIdx.x;
    int nwg = gridDim.x;
    int lb  = ((nwg & 7) == 0) ? ((bid & 7) * (nwg >> 3) + (bid >> 3)) : bid;

    int r = lb * RPB + lane;
    bool active = (r < n_ray);
    int rc = active ? r : (n_ray - 1);      // clamped for loads

    // ---- uniform: M inverse via adjugate ----
    float m00 = Mptr[0], m01 = Mptr[1], m02 = Mptr[2];
    float m10 = Mptr[3], m11 = Mptr[4], m12 = Mptr[5];
    float m20 = Mptr[6], m21 = Mptr[7], m22 = Mptr[8];
    float det = m00*(m11*m22 - m12*m21) - m01*(m10*m22 - m12*m20)
              + m02*(m10*m21 - m11*m20);
    float idet = 1.0f / det;
    float i00 =  (m11*m22 - m12*m21)*idet;
    float i01 = -(m01*m22 - m02*m21)*idet;
    float i02 =  (m01*m12 - m02*m11)*idet;
    float i10 = -(m10*m22 - m12*m20)*idet;
    float i11 =  (m00*m22 - m02*m20)*idet;
    float i12 = -(m00*m12 - m02*m10)*idet;
    float i20 =  (m10*m21 - m11*m20)*idet;
    float i21 = -(m00*m21 - m01*m20)*idet;
    float i22 =  (m00*m11 - m01*m10)*idet;

    float bx = bptr[0], by = bptr[1], bz = bptr[2];

    float sxw = src[3*rc+0], syw = src[3*rc+1], szw = src[3*rc+2];
    float exw = dst[3*rc+0], eyw = dst[3*rc+1], ezw = dst[3*rc+2];

    float wxw = exw - sxw, wyw = eyw - syw, wzw = ezw - szw;
    float ray_len = sqrtf(wxw*wxw + wyw*wyw + wzw*wzw);

    float ux = sxw - bx, uy = syw - by, uz = szw - bz;
    float p0x = i00*ux + i01*uy + i02*uz;
    float p0y = i10*ux + i11*uy + i12*uz;
    float p0z = i20*ux + i21*uy + i22*uz;
    float vx = exw - bx, vy = eyw - by, vz = ezw - bz;
    float p1x = i00*vx + i01*vy + i02*vz;
    float p1y = i10*vx + i11*vy + i12*vz;
    float p1z = i20*vx + i21*vy + i22*vz;

    float dx = p1x - p0x, dy = p1y - p0y, dz = p1z - p0z;

    bool parx = fabsf(dx) < EPS_F;
    bool pary = fabsf(dy) < EPS_F;
    bool parz = fabsf(dz) < EPS_F;

    // ---- slab intersection ----
    float tmin = 0.0f, tmax = 1.0f;
    if (parx) {
        bool inside = (p0x >= 0.0f) && (p0x <= (float)NV);
        tmin = fmaxf(tmin, inside ? 0.0f : BIG_F);
        tmax = fminf(tmax, inside ? 1.0f : -BIG_F);
    } else {
        float t0 = (0.0f - p0x) / dx, t1 = ((float)NV - p0x) / dx;
        tmin = fmaxf(tmin, fminf(t0, t1));
        tmax = fminf(tmax, fmaxf(t0, t1));
    }
    if (pary) {
        bool inside = (p0y >= 0.0f) && (p0y <= (float)NV);
        tmin = fmaxf(tmin, inside ? 0.0f : BIG_F);
        tmax = fminf(tmax, inside ? 1.0f : -BIG_F);
    } else {
        float t0 = (0.0f - p0y) / dy, t1 = ((float)NV - p0y) / dy;
        tmin = fmaxf(tmin, fminf(t0, t1));
        tmax = fminf(tmax, fmaxf(t0, t1));
    }
    if (parz) {
        bool inside = (p0z >= 0.0f) && (p0z <= (float)NV);
        tmin = fmaxf(tmin, inside ? 0.0f : BIG_F);
        tmax = fminf(tmax, inside ? 1.0f : -BIG_F);
    } else {
        float t0 = (0.0f - p0z) / dz, t1 = ((float)NV - p0z) / dz;
        tmin = fmaxf(tmin, fminf(t0, t1));
        tmax = fminf(tmax, fmaxf(t0, t1));
    }

    float acc = 0.0f;

    if (active && (tmax > tmin)) {
        // per-ray DDA constants (shared by both streams)
        float invx = parx ? 0.0f : (1.0f / dx);
        float invy = pary ? 0.0f : (1.0f / dy);
        float invz = parz ? 0.0f : (1.0f / dz);
        float adx = fabsf(invx), ady = fabsf(invy), adz = fabsf(invz);
        int ox = parx ? 0 : (dx > 0.0f ?  NVSQ : -NVSQ);
        int oy = pary ? 0 : (dy > 0.0f ?  NV   : -NV);
        int oz = parz ? 0 : (dz > 0.0f ?  1    : -1);

        float span = (tmax - tmin) * (1.0f / (float)SPLIT);

        auto dda_init = [&](float ta, float &tx, float &ty, float &tz, int &flat) {
            int ix, iy, iz;
            if (!parx) {
                float q = p0x + ta * dx;
                int pl;
                if (dx > 0.0f) { pl = (int)floorf(q) + 1; ix = pl - 1; }
                else           { pl = (int)ceilf(q)  - 1; ix = pl; }
                tx = ((float)pl - p0x) * invx;
            } else { tx = BIG_F; ix = (int)floorf(p0x); }
            if (!pary) {
                float q = p0y + ta * dy;
                int pl;
                if (dy > 0.0f) { pl = (int)floorf(q) + 1; iy = pl - 1; }
                else           { pl = (int)ceilf(q)  - 1; iy = pl; }
                ty = ((float)pl - p0y) * invy;
            } else { ty = BIG_F; iy = (int)floorf(p0y); }
            if (!parz) {
                float q = p0z + ta * dz;
                int pl;
                if (dz > 0.0f) { pl = (int)floorf(q) + 1; iz = pl - 1; }
                else           { pl = (int)ceilf(q)  - 1; iz = pl; }
                tz = ((float)pl - p0z) * invz;
            } else { tz = BIG_F; iz = (int)floorf(p0z); }
            flat = ix * NVSQ + iy * NV + iz;
        };

        // ---- stream A: sub-range `sub`; stream B: sub-range `sub+8` ----
        float taA = tmin + (float)sub * span;
        float tbA = tmin + (float)(sub + 1) * span;
        float taB = tmin + (float)(sub + WPB) * span;
        float tbB = (sub == WPB - 1) ? tmax : (tmin + (float)(sub + WPB + 1) * span);

        float txA, tyA, tzA; int flatA;
        float txB, tyB, tzB; int flatB;
        dda_init(taA, txA, tyA, tzA, flatA);
        dda_init(taB, txB, tyB, tzB, flatB);

        // prime both pipelines
        unsigned ufA = (unsigned)flatA;  bool vokA = (ufA < NV3);
        float vldA = vol[vokA ? ufA : 0u];
        unsigned ufB = (unsigned)flatB;  bool vokB = (ufB < NV3);
        float vldB = vol[vokB ? ufB : 0u];

        float tcurA = taA, tcurB = taB;
        float accA = 0.0f, accB = 0.0f;

        const int MAXIT = 3 * (NV + 1) / SPLIT + 16;

        for (int it = 0; it < MAXIT; ++it) {
            if (!(tcurA < tbA) && !(tcurB < tbB)) break;

            // ---- stream A: advance + issue next load ----
            float tnA = fminf(fminf(txA, tyA), fminf(tzA, tbA));
            float dtA = tnA - tcurA;
            bool sxA = (txA <= tnA), syA = (tyA <= tnA), szA = (tzA <= tnA);
            txA += sxA ? adx : 0.0f;
            tyA += syA ? ady : 0.0f;
            tzA += szA ? adz : 0.0f;
            flatA += (sxA ? ox : 0) + (syA ? oy : 0) + (szA ? oz : 0);
            unsigned ufAn = (unsigned)flatA;
            bool vokAn = (ufAn < NV3);
            float vldAn = vol[vokAn ? ufAn : 0u];

            // ---- stream B: advance + issue next load ----
            float tnB = fminf(fminf(txB, tyB), fminf(tzB, tbB));
            float dtB = tnB - tcurB;
            bool sxB = (txB <= tnB), syB = (tyB <= tnB), szB = (tzB <= tnB);
            txB += sxB ? adx : 0.0f;
            tyB += syB ? ady : 0.0f;
            tzB += szB ? adz : 0.0f;
            flatB += (sxB ? ox : 0) + (syB ? oy : 0) + (szB ? oz : 0);
            unsigned ufBn = (unsigned)flatB;
            bool vokBn = (ufBn < NV3);
            float vldBn = vol[vokBn ? ufBn : 0u];

            // ---- consume previous loads ----
            accA = fmaf(dtA, vokA ? vldA : 0.0f, accA);
            accB = fmaf(dtB, vokB ? vldB : 0.0f, accB);

            vldA = vldAn; vokA = vokAn; tcurA = tnA;
            vldB = vldBn; vokB = vokBn; tcurB = tnB;
        }

        acc = accA + accB;
    }

    // ---- block reduction over the 8 waves (16 sub-ranges): LDS [8][64] ----
    __shared__ float part[WPB][RPB];
    part[sub][lane] = acc;
    __syncthreads();

    if (threadIdx.x < RPB && active) {
        float s = 0.0f;
        #pragma unroll
        for (int w = 0; w < WPB; ++w) s += part[w][threadIdx.x];
        out[r] = s * ray_len;
    }
}

extern "C" void kernel_launch(void* const* d_in, const int* in_sizes, int n_in,
                              void* d_out, int out_size, void* d_ws, size_t ws_size,
                              hipStream_t stream) {
    const float* vol  = (const float*)d_in[0];
    const float* M    = (const float*)d_in[1];
    const float* bvec = (const float*)d_in[2];
    const float* src  = (const float*)d_in[3];
    const float* dst  = (const float*)d_in[4];
    float* out = (float*)d_out;

    int n_ray = in_sizes[3] / 3;
    int nblk = (n_ray + RPB - 1) / RPB;
    dim3 block(512);
    dim3 grid((unsigned)nblk);
    hipLaunchKernelGGL(siddon_fwd_kernel, grid, block, 0, stream,
                       vol, M, bvec, src, dst, out, n_ray);
}

// Round 7
// 17.802 us; speedup vs baseline: 1.0755x; 1.0755x over previous
//
#include <hip/hip_runtime.h>
#include <math.h>

// Siddon exact forward projector — incremental (Amanatides-Woo) traversal.
// Block = 512 threads = 8 waves = 64 consecutive rays x 8 t-sub-ranges.
// Round-6: __launch_bounds__(512,8) forces <=64 VGPR (8 waves/SIMD), leaner
// loop body (single dt-gate instead of addr+val selects, min3-shaped mins).

constexpr int      NV    = 128;
constexpr int      NVSQ  = NV * NV;
constexpr unsigned NV3   = (unsigned)NV * NV * NV;
constexpr float    EPS_F = 1e-12f;
constexpr float    BIG_F = 1e9f;
constexpr int      SPLIT = 8;    // sub-ranges per ray = waves per block
constexpr int      RPB   = 64;   // rays per block (= lanes per wave)

__global__ __launch_bounds__(512, 8)
void siddon_fwd_kernel(const float* __restrict__ vol,
                       const float* __restrict__ Mptr,
                       const float* __restrict__ bptr,
                       const float* __restrict__ src,
                       const float* __restrict__ dst,
                       float* __restrict__ out,
                       int n_ray)
{
    int lane = threadIdx.x & 63;
    int sub  = threadIdx.x >> 6;            // 0..7, one sub-range per wave

    // ---- XCD-aware block swizzle (bijective when gridDim.x % 8 == 0) ----
    int bid = blockIdx.x;
    int nwg = gridDim.x;
    int lb  = ((nwg & 7) == 0) ? ((bid & 7) * (nwg >> 3) + (bid >> 3)) : bid;

    int r = lb * RPB + lane;
    bool active = (r < n_ray);
    int rc = active ? r : (n_ray - 1);      // clamped for loads

    // ---- uniform: M inverse via adjugate ----
    float m00 = Mptr[0], m01 = Mptr[1], m02 = Mptr[2];
    float m10 = Mptr[3], m11 = Mptr[4], m12 = Mptr[5];
    float m20 = Mptr[6], m21 = Mptr[7], m22 = Mptr[8];
    float det = m00*(m11*m22 - m12*m21) - m01*(m10*m22 - m12*m20)
              + m02*(m10*m21 - m11*m20);
    float idet = 1.0f / det;
    float i00 =  (m11*m22 - m12*m21)*idet;
    float i01 = -(m01*m22 - m02*m21)*idet;
    float i02 =  (m01*m12 - m02*m11)*idet;
    float i10 = -(m10*m22 - m12*m20)*idet;
    float i11 =  (m00*m22 - m02*m20)*idet;
    float i12 = -(m00*m12 - m02*m10)*idet;
    float i20 =  (m10*m21 - m11*m20)*idet;
    float i21 = -(m00*m21 - m01*m20)*idet;
    float i22 =  (m00*m11 - m01*m10)*idet;

    float bx = bptr[0], by = bptr[1], bz = bptr[2];

    float sxw = src[3*rc+0], syw = src[3*rc+1], szw = src[3*rc+2];
    float exw = dst[3*rc+0], eyw = dst[3*rc+1], ezw = dst[3*rc+2];

    float wxw = exw - sxw, wyw = eyw - syw, wzw = ezw - szw;
    float ray_len = sqrtf(wxw*wxw + wyw*wyw + wzw*wzw);

    float ux = sxw - bx, uy = syw - by, uz = szw - bz;
    float p0x = i00*ux + i01*uy + i02*uz;
    float p0y = i10*ux + i11*uy + i12*uz;
    float p0z = i20*ux + i21*uy + i22*uz;
    float vx = exw - bx, vy = eyw - by, vz = ezw - bz;
    float p1x = i00*vx + i01*vy + i02*vz;
    float p1y = i10*vx + i11*vy + i12*vz;
    float p1z = i20*vx + i21*vy + i22*vz;

    float dx = p1x - p0x, dy = p1y - p0y, dz = p1z - p0z;

    bool parx = fabsf(dx) < EPS_F;
    bool pary = fabsf(dy) < EPS_F;
    bool parz = fabsf(dz) < EPS_F;

    // ---- slab intersection ----
    float tmin = 0.0f, tmax = 1.0f;
    if (parx) {
        bool inside = (p0x >= 0.0f) && (p0x <= (float)NV);
        tmin = fmaxf(tmin, inside ? 0.0f : BIG_F);
        tmax = fminf(tmax, inside ? 1.0f : -BIG_F);
    } else {
        float t0 = (0.0f - p0x) / dx, t1 = ((float)NV - p0x) / dx;
        tmin = fmaxf(tmin, fminf(t0, t1));
        tmax = fminf(tmax, fmaxf(t0, t1));
    }
    if (pary) {
        bool inside = (p0y >= 0.0f) && (p0y <= (float)NV);
        tmin = fmaxf(tmin, inside ? 0.0f : BIG_F);
        tmax = fminf(tmax, inside ? 1.0f : -BIG_F);
    } else {
        float t0 = (0.0f - p0y) / dy, t1 = ((float)NV - p0y) / dy;
        tmin = fmaxf(tmin, fminf(t0, t1));
        tmax = fminf(tmax, fmaxf(t0, t1));
    }
    if (parz) {
        bool inside = (p0z >= 0.0f) && (p0z <= (float)NV);
        tmin = fmaxf(tmin, inside ? 0.0f : BIG_F);
        tmax = fminf(tmax, inside ? 1.0f : -BIG_F);
    } else {
        float t0 = (0.0f - p0z) / dz, t1 = ((float)NV - p0z) / dz;
        tmin = fmaxf(tmin, fminf(t0, t1));
        tmax = fminf(tmax, fmaxf(t0, t1));
    }

    float acc = 0.0f;

    if (active && (tmax > tmin)) {
        float span = (tmax - tmin) * (1.0f / (float)SPLIT);
        float ta = tmin + (float)sub * span;
        float tb = (sub == SPLIT - 1) ? tmax : (tmin + (float)(sub + 1) * span);

        // ---- DDA init at t = ta ----
        float tx = BIG_F, ty = BIG_F, tz = BIG_F;
        float adx = 0.0f, ady = 0.0f, adz = 0.0f;
        int ix, iy, iz;
        int ox = 0, oy = 0, oz = 0;

        if (!parx) {
            float invx = 1.0f / dx;
            adx = fabsf(invx);
            float q = p0x + ta * dx;
            int pl;
            if (dx > 0.0f) { pl = (int)floorf(q) + 1; ix = pl - 1; ox =  NVSQ; }
            else           { pl = (int)ceilf(q)  - 1; ix = pl;     ox = -NVSQ; }
            tx = ((float)pl - p0x) * invx;
        } else {
            ix = (int)floorf(p0x);
        }
        if (!pary) {
            float invy = 1.0f / dy;
            ady = fabsf(invy);
            float q = p0y + ta * dy;
            int pl;
            if (dy > 0.0f) { pl = (int)floorf(q) + 1; iy = pl - 1; oy =  NV; }
            else           { pl = (int)ceilf(q)  - 1; iy = pl;     oy = -NV; }
            ty = ((float)pl - p0y) * invy;
        } else {
            iy = (int)floorf(p0y);
        }
        if (!parz) {
            float invz = 1.0f / dz;
            adz = fabsf(invz);
            float q = p0z + ta * dz;
            int pl;
            if (dz > 0.0f) { pl = (int)floorf(q) + 1; iz = pl - 1; oz =  1; }
            else           { pl = (int)ceilf(q)  - 1; iz = pl;     oz = -1; }
            tz = ((float)pl - p0z) * invz;
        } else {
            iz = (int)floorf(p0z);
        }

        int flat = ix * NVSQ + iy * NV + iz;

        // ---- software-pipelined traversal (1-deep) ----
        unsigned uf = (unsigned)flat;
        bool vok = (uf < NV3);
        float vld = vol[uf < NV3 ? uf : (NV3 - 1u)];

        float tcur = ta;
        const int MAXIT = 3 * (NV + 1) / SPLIT + 32;

        for (int it = 0; it < MAXIT; ++it) {
            if (!(tcur < tb)) break;

            float tn = fminf(fminf(tx, ty), fminf(tz, tb));  // min3 + min
            float dt = tn - tcur;
            float dte = vok ? dt : 0.0f;                     // single gate

            bool sx = (tx <= tn), sy = (ty <= tn), sz = (tz <= tn);
            tx += sx ? adx : 0.0f;
            ty += sy ? ady : 0.0f;
            tz += sz ? adz : 0.0f;
            flat += (sx ? ox : 0) + (sy ? oy : 0) + (sz ? oz : 0);

            unsigned ufn = (unsigned)flat;
            bool vokn = (ufn < NV3);
            float vldn = vol[ufn < NV3 ? ufn : (NV3 - 1u)];  // issue next gather EARLY

            acc = fmaf(dte, vld, acc);                        // consume PREVIOUS gather

            vld = vldn;
            vok = vokn;
            tcur = tn;
        }
    }

    // ---- block reduction over the 8 sub-ranges: LDS [8][64], conflict-free ----
    __shared__ float part[SPLIT][RPB];
    part[sub][lane] = acc;
    __syncthreads();

    if (threadIdx.x < RPB && active) {
        float s = 0.0f;
        #pragma unroll
        for (int w = 0; w < SPLIT; ++w) s += part[w][threadIdx.x];
        out[r] = s * ray_len;
    }
}

extern "C" void kernel_launch(void* const* d_in, const int* in_sizes, int n_in,
                              void* d_out, int out_size, void* d_ws, size_t ws_size,
                              hipStream_t stream) {
    const float* vol  = (const float*)d_in[0];
    const float* M    = (const float*)d_in[1];
    const float* bvec = (const float*)d_in[2];
    const float* src  = (const float*)d_in[3];
    const float* dst  = (const float*)d_in[4];
    float* out = (float*)d_out;

    int n_ray = in_sizes[3] / 3;
    int nblk = (n_ray + RPB - 1) / RPB;
    dim3 block(512);
    dim3 grid((unsigned)nblk);
    hipLaunchKernelGGL(siddon_fwd_kernel, grid, block, 0, stream,
                       vol, M, bvec, src, dst, out, n_ray);
}